// Round 4
// baseline (556.867 us; speedup 1.0000x reference)
//
#include <hip/hip_runtime.h>
#include <stdint.h>

// GRID=4096, windows (128,256,512) centered at (2048,2048).
// Output = [3,4096,4096] float masks flat, then 3 counts.
#define GRID_N 4096
#define CELL_BLOCKS 1344    // 64 + 256 + 1024 blocks of 256 (one thread per cell)
#define TILE_BLOCKS 336     // 16 + 64 + 256 tiles of 32x32
#define NUM_EDGES 19712     // boundary edges: 768 + 3584 + 15360
#define ZERO_BLOCKS 8192

typedef float vfloat4 __attribute__((ext_vector_type(4)));

// ---- window decode for cell-per-thread kernels (256 threads/block) ----
__device__ inline void decode_block(int b, int& w, int& S, int& lg, int& off,
                                    int& woff, int& baseblk) {
    if (b < 64)       { w = 0; S = 128; lg = 7; off = 1984; woff = 0;     baseblk = 0;   }
    else if (b < 320) { w = 1; S = 256; lg = 8; off = 1920; woff = 16384; baseblk = 64;  }
    else              { w = 2; S = 512; lg = 9; off = 1792; woff = 81920; baseblk = 320; }
}

// ---- tile decode (32x32 tile per block) ----
__device__ inline void decode_tile(int b, int& S, int& lg, int& off, int& woff,
                                   int& tileR, int& tileC) {
    int t, tsh;
    if (b < 16)      { S = 128; lg = 7; off = 1984; woff = 0;     t = b;      tsh = 2; }
    else if (b < 80) { S = 256; lg = 8; off = 1920; woff = 16384; t = b - 16; tsh = 3; }
    else             { S = 512; lg = 9; off = 1792; woff = 81920; t = b - 80; tsh = 4; }
    tileR = t >> tsh;
    tileC = t & ((1 << tsh) - 1);
}

// ---- global union-find with path-halving (device scope) ----
// Invariant: L[x] is always an ancestor-of-or-equal-to x with index <= x
// (unions attach larger root under smaller). Halving CAS writes only an
// existing grandparent, preserving the invariant under races.
__device__ inline int uf_find(int* L, int a) {
    while (true) {
        int p = __hip_atomic_load(&L[a], __ATOMIC_RELAXED, __HIP_MEMORY_SCOPE_AGENT);
        if (p == a) return a;
        int gp = __hip_atomic_load(&L[p], __ATOMIC_RELAXED, __HIP_MEMORY_SCOPE_AGENT);
        if (gp == p) return p;
        __hip_atomic_compare_exchange_strong(&L[a], &p, gp,
            __ATOMIC_RELAXED, __ATOMIC_RELAXED, __HIP_MEMORY_SCOPE_AGENT);
        a = gp;
    }
}
__device__ inline void uf_union(int* L, int a, int b) {
    while (true) {
        a = uf_find(L, a);
        b = uf_find(L, b);
        if (a == b) return;
        if (a < b) { int t = a; a = b; b = t; }   // a > b: attach a under b
        int old = atomicMin(&L[a], b);
        if (old == a) return;                      // was a root, attached
        a = old;                                   // lost race: merge old link too
    }
}

// ---- LDS union-find (workgroup scope, used only inside one tile) ----
__device__ inline int lfind(int* lab, int a) {
    int p = __hip_atomic_load(&lab[a], __ATOMIC_RELAXED, __HIP_MEMORY_SCOPE_WORKGROUP);
    while (p != a) {
        a = p;
        p = __hip_atomic_load(&lab[a], __ATOMIC_RELAXED, __HIP_MEMORY_SCOPE_WORKGROUP);
    }
    return a;
}
__device__ inline void lunion(int* lab, int a, int b) {
    while (true) {
        a = lfind(lab, a);
        b = lfind(lab, b);
        if (a == b) return;
        if (a < b) { int t = a; a = b; b = t; }
        int old = atomicMin(&lab[a], b);
        if (old == a) return;
        a = old;
    }
}

// K1: first TILE_BLOCKS blocks: per-tile CCL in LDS -> depth-1 global forest
// (window-linear indices), blocked = -1. Remaining ZERO_BLOCKS blocks:
// zero-fill the whole 201 MB output (nontemporal float4) + count slots.
// Tile CCL (~8 us) hides under the fill (~33 us).
__global__ void k_init_zero(const float* __restrict__ mask, int* __restrict__ L,
                            float* __restrict__ out, int out_size) {
    int b = blockIdx.x;
    if (b < TILE_BLOCKS) {
        int S, lg, off, woff, tileR, tileC;
        decode_tile(b, S, lg, off, woff, tileR, tileC);
        __shared__ int lab[1024];

        #pragma unroll
        for (int k = 0; k < 4; k++) {
            int l = threadIdx.x + k * 256;
            int lr = l >> 5, lc = l & 31;
            size_t g = (size_t)(off + tileR * 32 + lr) * GRID_N
                     + (size_t)(off + tileC * 32 + lc);
            lab[l] = (mask[g] == 0.0f) ? l : -1;
        }
        __syncthreads();

        #pragma unroll
        for (int k = 0; k < 4; k++) {
            int l = threadIdx.x + k * 256;
            if (lab[l] == -1) continue;
            int lr = l >> 5, lc = l & 31;
            if (lc + 1 < 32 && lab[l + 1] != -1)  lunion(lab, l, l + 1);
            if (lr + 1 < 32 && lab[l + 32] != -1) lunion(lab, l, l + 32);
        }
        __syncthreads();

        #pragma unroll
        for (int k = 0; k < 4; k++) {
            int l = threadIdx.x + k * 256;
            int lr = l >> 5, lc = l & 31;
            int gidx = (tileR * 32 + lr) * S + tileC * 32 + lc;
            if (lab[l] == -1) {
                L[woff + gidx] = -1;
            } else {
                int r = lfind(lab, l);
                int rr = r >> 5, rc = r & 31;
                L[woff + gidx] = (tileR * 32 + rr) * S + tileC * 32 + rc;
            }
        }
    } else {
        long long n4 = (long long)(out_size >> 2);
        long long i = (long long)(b - TILE_BLOCKS) * 256 + threadIdx.x;
        long long stride = (long long)ZERO_BLOCKS * 256;
        vfloat4* o4 = (vfloat4*)out;
        vfloat4 z = (vfloat4)(0.0f);
        for (; i < n4; i += stride) __builtin_nontemporal_store(z, &o4[i]);
        long long t = (long long)(b - TILE_BLOCKS) * 256 + threadIdx.x;
        long long tail = (long long)out_size - n4 * 4;
        if (t < tail) out[n4 * 4 + t] = 0.0f;   // the 3 count slots
    }
}

// Edge decode: e in [0, NUM_EDGES). Ranges: [0,384) w0-h, [384,768) w0-v,
// [768,2560) w1-h, [2560,4352) w1-v, [4352,12032) w2-h, [12032,19712) w2-v.
__device__ inline void decode_edge(int e, int*& Lw, int& a, int& n, int* L) {
    int S, lg, woff, i; bool horiz;
    if (e < 768)        { S = 128; lg = 7; woff = 0;     horiz = e < 384;   i = horiz ? e : e - 384; }
    else if (e < 4352)  { S = 256; lg = 8; woff = 16384; horiz = e < 2560;  i = horiz ? e - 768 : e - 2560; }
    else                { S = 512; lg = 9; woff = 81920; horiz = e < 12032; i = horiz ? e - 4352 : e - 12032; }
    int bi = i >> lg;
    Lw = L + woff;
    if (horiz) { int r = i & (S - 1); int c = bi * 32 + 31; a = r * S + c; n = a + 1; }
    else       { int c = i & (S - 1); int r = bi * 32 + 31; a = r * S + c; n = a + S; }
}

// K2: single-block inter-tile merge. 19712 boundary edges on a depth-1 forest;
// path-halving keeps trees shallow; one XCD's L2 holds all 1.35 MB of labels.
// Second sweep compresses edge-endpoint paths so tile roots point ~directly
// at final roots before k_write's 344K finds.
__global__ void k_merge(int* __restrict__ L) {
    for (int e = threadIdx.x; e < NUM_EDGES; e += blockDim.x) {
        int *Lw, a, n;
        decode_edge(e, Lw, a, n, L);
        if (Lw[a] != -1 && Lw[n] != -1) uf_union(Lw, a, n);
    }
    __syncthreads();
    for (int e = threadIdx.x; e < NUM_EDGES; e += blockDim.x) {
        int *Lw, a, n;
        decode_edge(e, Lw, a, n, L);
        if (Lw[a] != -1) { int r = uf_find(Lw, a); Lw[a] = r; }
        if (Lw[n] != -1) { int r = uf_find(Lw, n); Lw[n] = r; }
    }
}

// K3: reach = free && find(cell)==find(center); scatter window masks; counts
// via ballot-popcount -> one float atomicAdd per block (counts < 2^24, exact).
__global__ void k_write(int* __restrict__ L, float* __restrict__ out) {
    int b = blockIdx.x;
    int w, S, lg, off, woff, baseblk;
    decode_block(b, w, S, lg, off, woff, baseblk);
    int idx = (b - baseblk) * 256 + threadIdx.x;
    int* Lw = L + woff;

    __shared__ int rootC;
    __shared__ float wsum[4];
    if (threadIdx.x == 0) {
        int centerIdx = (S >> 1) * S + (S >> 1);   // center is always free (setup)
        rootC = uf_find(Lw, centerIdx);
    }
    __syncthreads();

    int lab = Lw[idx];
    bool reach = false;
    if (lab != -1) {
        int root = uf_find(Lw, idx);
        reach = (root == rootC);
    }
    int r = idx >> lg;
    int c = idx & (S - 1);
    size_t go = (size_t)w * GRID_N * GRID_N + (size_t)(off + r) * GRID_N + (size_t)(off + c);
    out[go] = reach ? 1.0f : 0.0f;

    unsigned long long m = __ballot(reach);
    int lane = threadIdx.x & 63;
    int wv = threadIdx.x >> 6;
    if (lane == 0) wsum[wv] = (float)__popcll(m);
    __syncthreads();
    if (threadIdx.x == 0) {
        float s = wsum[0] + wsum[1] + wsum[2] + wsum[3];
        atomicAdd(&out[(size_t)3 * GRID_N * GRID_N + w], s);
    }
}

extern "C" void kernel_launch(void* const* d_in, const int* in_sizes, int n_in,
                              void* d_out, int out_size, void* d_ws, size_t ws_size,
                              hipStream_t stream) {
    const float* mask = (const float*)d_in[0];
    float* out = (float*)d_out;
    int* L = (int*)d_ws;   // 344064 * 4 B = 1.35 MB of workspace

    k_init_zero<<<TILE_BLOCKS + ZERO_BLOCKS, 256, 0, stream>>>(mask, L, out, out_size);
    k_merge<<<1, 1024, 0, stream>>>(L);
    k_write<<<CELL_BLOCKS, 256, 0, stream>>>(L, out);
}

// Round 5
// 272.980 us; speedup vs baseline: 2.0400x; 2.0400x over previous
//
#include <hip/hip_runtime.h>
#include <stdint.h>

// GRID=4096, windows (128,256,512) centered at (2048,2048).
// Output = [3,4096,4096] float masks flat, then 3 counts.
#define GRID_N 4096
#define CELL_BLOCKS 1344    // 64 + 256 + 1024 blocks of 256 (one thread per cell)
#define TILE_BLOCKS 336     // 16 + 64 + 256 tiles of 32x32
#define NUM_EDGES 19712     // boundary-cell edges: 768 + 3584 + 15360
#define EDGE_BLOCKS 77      // 19712 / 256
#define ZERO_BLOCKS 8192

typedef float vfloat4 __attribute__((ext_vector_type(4)));

// ---- window decode for cell-per-thread kernels (256 threads/block) ----
__device__ inline void decode_block(int b, int& w, int& S, int& lg, int& off,
                                    int& woff, int& baseblk) {
    if (b < 64)       { w = 0; S = 128; lg = 7; off = 1984; woff = 0;     baseblk = 0;   }
    else if (b < 320) { w = 1; S = 256; lg = 8; off = 1920; woff = 16384; baseblk = 64;  }
    else              { w = 2; S = 512; lg = 9; off = 1792; woff = 81920; baseblk = 320; }
}

// ---- tile decode (32x32 tile per block) ----
__device__ inline void decode_tile(int b, int& S, int& lg, int& off, int& woff,
                                   int& tileR, int& tileC) {
    int t, tsh;
    if (b < 16)      { S = 128; lg = 7; off = 1984; woff = 0;     t = b;      tsh = 2; }
    else if (b < 80) { S = 256; lg = 8; off = 1920; woff = 16384; t = b - 16; tsh = 3; }
    else             { S = 512; lg = 9; off = 1792; woff = 81920; t = b - 80; tsh = 4; }
    tileR = t >> tsh;
    tileC = t & ((1 << tsh) - 1);
}

// ---- global union-find with path-halving (device scope) ----
// Invariant: parent < node always (unions attach larger root under smaller),
// so walks strictly decrease and terminate; halving CAS writes an existing
// grandparent, preserving the invariant under races.
__device__ inline int uf_find(int* L, int a) {
    while (true) {
        int p = __hip_atomic_load(&L[a], __ATOMIC_RELAXED, __HIP_MEMORY_SCOPE_AGENT);
        if (p == a) return a;
        int gp = __hip_atomic_load(&L[p], __ATOMIC_RELAXED, __HIP_MEMORY_SCOPE_AGENT);
        if (gp == p) return p;
        __hip_atomic_compare_exchange_strong(&L[a], &p, gp,
            __ATOMIC_RELAXED, __ATOMIC_RELAXED, __HIP_MEMORY_SCOPE_AGENT);
        a = gp;
    }
}
__device__ inline void uf_union(int* L, int a, int b) {
    while (true) {
        a = uf_find(L, a);
        b = uf_find(L, b);
        if (a == b) return;
        if (a < b) { int t = a; a = b; b = t; }   // a > b: attach a under b
        int old = atomicMin(&L[a], b);
        if (old == a) return;                      // was a root, attached
        a = old;                                   // lost race: merge old link too
    }
}

// ---- LDS union-find (workgroup scope, only inside one tile) ----
__device__ inline int lfind(int* lab, int a) {
    int p = __hip_atomic_load(&lab[a], __ATOMIC_RELAXED, __HIP_MEMORY_SCOPE_WORKGROUP);
    while (p != a) {
        a = p;
        p = __hip_atomic_load(&lab[a], __ATOMIC_RELAXED, __HIP_MEMORY_SCOPE_WORKGROUP);
    }
    return a;
}
__device__ inline void lunion(int* lab, int a, int b) {
    while (true) {
        a = lfind(lab, a);
        b = lfind(lab, b);
        if (a == b) return;
        if (a < b) { int t = a; a = b; b = t; }
        int old = atomicMin(&lab[a], b);
        if (old == a) return;
        a = old;
    }
}

// K1: per-tile CCL in LDS -> depth-1 global forest (window-linear indices),
// blocked = -1.
__global__ void k_local(const float* __restrict__ mask, int* __restrict__ L) {
    int S, lg, off, woff, tileR, tileC;
    decode_tile(blockIdx.x, S, lg, off, woff, tileR, tileC);
    __shared__ int lab[1024];

    #pragma unroll
    for (int k = 0; k < 4; k++) {
        int l = threadIdx.x + k * 256;
        int lr = l >> 5, lc = l & 31;
        size_t g = (size_t)(off + tileR * 32 + lr) * GRID_N
                 + (size_t)(off + tileC * 32 + lc);
        lab[l] = (mask[g] == 0.0f) ? l : -1;
    }
    __syncthreads();

    #pragma unroll
    for (int k = 0; k < 4; k++) {
        int l = threadIdx.x + k * 256;
        if (lab[l] == -1) continue;
        int lr = l >> 5, lc = l & 31;
        if (lc + 1 < 32 && lab[l + 1] != -1)  lunion(lab, l, l + 1);
        if (lr + 1 < 32 && lab[l + 32] != -1) lunion(lab, l, l + 32);
    }
    __syncthreads();

    #pragma unroll
    for (int k = 0; k < 4; k++) {
        int l = threadIdx.x + k * 256;
        int lr = l >> 5, lc = l & 31;
        int gidx = (tileR * 32 + lr) * S + tileC * 32 + lc;
        if (lab[l] == -1) {
            L[woff + gidx] = -1;
        } else {
            int r = lfind(lab, l);
            int rr = r >> 5, rc = r & 31;
            L[woff + gidx] = (tileR * 32 + rr) * S + tileC * 32 + rc;
        }
    }
}

// K2: first EDGE_BLOCKS blocks union tile-boundary edges (one edge cell per
// thread, wave-shuffle dedupe of identical label pairs -> ~1-2K real unions);
// remaining blocks zero-fill the 201 MB output with nontemporal float4.
// Edge ordering: within each boundary line, the 32 cells of one tile-edge are
// consecutive in e, so lane-1 shuffle compares within the same tile edge.
__global__ void k_zero_merge(int* __restrict__ L, float* __restrict__ out,
                             int out_size) {
    int b = blockIdx.x;
    if (b < EDGE_BLOCKS) {
        int e = b * 256 + threadIdx.x;
        // ranges: [0,384) w0-v, [384,768) w0-h, [768,2560) w1-v,
        //         [2560,4352) w1-h, [4352,12032) w2-v, [12032,19712) w2-h
        int S, lg, woff, i; bool vert;
        if (e < 768)        { S = 128; lg = 7; woff = 0;     vert = e < 384;   i = vert ? e : e - 384; }
        else if (e < 4352)  { S = 256; lg = 8; woff = 16384; vert = e < 2560;  i = vert ? e - 768 : e - 2560; }
        else                { S = 512; lg = 9; woff = 81920; vert = e < 12032; i = vert ? e - 4352 : e - 12032; }
        int line = i >> lg;            // which boundary line
        int pos = i & (S - 1);         // position along the line
        int* Lw = L + woff;
        int a, n;
        if (vert) { int c = line * 32 + 31; a = pos * S + c; n = a + 1; }
        else      { int r = line * 32 + 31; a = r * S + pos; n = a + S; }
        int la = Lw[a];                // tile-root labels; stable during K2
        int ln = Lw[n];                // (halving never rewrites leaf cells)
        int pla = __shfl_up(la, 1);
        int pln = __shfl_up(ln, 1);
        bool first = ((pos & 31) == 0);   // first cell of this tile edge
        if (la != -1 && ln != -1 && (first || la != pla || ln != pln))
            uf_union(Lw, la, ln);
    } else {
        long long n4 = (long long)(out_size >> 2);
        long long i = (long long)(b - EDGE_BLOCKS) * 256 + threadIdx.x;
        long long stride = (long long)ZERO_BLOCKS * 256;
        vfloat4* o4 = (vfloat4*)out;
        vfloat4 z = (vfloat4)(0.0f);
        for (; i < n4; i += stride) __builtin_nontemporal_store(z, &o4[i]);
        long long t = (long long)(b - EDGE_BLOCKS) * 256 + threadIdx.x;
        long long tail = (long long)out_size - n4 * 4;
        if (t < tail) out[n4 * 4 + t] = 0.0f;   // the 3 count slots
    }
}

// K3: reach = free && find(cell)==find(center); scatter window masks; counts
// via ballot-popcount -> one float atomicAdd per block (counts < 2^24, exact).
__global__ void k_write(int* __restrict__ L, float* __restrict__ out) {
    int b = blockIdx.x;
    int w, S, lg, off, woff, baseblk;
    decode_block(b, w, S, lg, off, woff, baseblk);
    int idx = (b - baseblk) * 256 + threadIdx.x;
    int* Lw = L + woff;

    __shared__ int rootC;
    __shared__ float wsum[4];
    if (threadIdx.x == 0) {
        int centerIdx = (S >> 1) * S + (S >> 1);   // center is always free (setup)
        rootC = uf_find(Lw, centerIdx);
    }
    __syncthreads();

    int lab = Lw[idx];
    bool reach = false;
    if (lab != -1) {
        int root = uf_find(Lw, idx);
        reach = (root == rootC);
    }
    int r = idx >> lg;
    int c = idx & (S - 1);
    size_t go = (size_t)w * GRID_N * GRID_N + (size_t)(off + r) * GRID_N + (size_t)(off + c);
    out[go] = reach ? 1.0f : 0.0f;

    unsigned long long m = __ballot(reach);
    int lane = threadIdx.x & 63;
    int wv = threadIdx.x >> 6;
    if (lane == 0) wsum[wv] = (float)__popcll(m);
    __syncthreads();
    if (threadIdx.x == 0) {
        float s = wsum[0] + wsum[1] + wsum[2] + wsum[3];
        atomicAdd(&out[(size_t)3 * GRID_N * GRID_N + w], s);
    }
}

extern "C" void kernel_launch(void* const* d_in, const int* in_sizes, int n_in,
                              void* d_out, int out_size, void* d_ws, size_t ws_size,
                              hipStream_t stream) {
    const float* mask = (const float*)d_in[0];
    float* out = (float*)d_out;
    int* L = (int*)d_ws;   // 344064 * 4 B = 1.35 MB of workspace

    k_local<<<TILE_BLOCKS, 256, 0, stream>>>(mask, L);
    k_zero_merge<<<EDGE_BLOCKS + ZERO_BLOCKS, 256, 0, stream>>>(L, out, out_size);
    k_write<<<CELL_BLOCKS, 256, 0, stream>>>(L, out);
}